// Round 7
// baseline (146.677 us; speedup 1.0000x reference)
//
#include <hip/hip_runtime.h>
#include <hip/hip_bf16.h>

// B=2,T=64,V=32000,NH=32,HD=32. BT=128, M=4096 rows, D=32.
// Flash-attn formulation: Q=F (4096x32, pre-scaled by invt*log2e),
// K=V=vs (32000x32). S=Q.vs^T, P=exp2(S), out = P.vs / rowsum(P).
#define NV      32000
#define MROWS   4096
#define NSLICE  8
#define CHUNKS_PER_SLICE 125   // of 1000 total 32-v chunks
#define PART_STRIDE 1056       // 32x32 acc + 32 lsum

typedef __attribute__((ext_vector_type(8))) short short8;
typedef __attribute__((ext_vector_type(16))) float f32x16;
typedef __attribute__((ext_vector_type(4))) float f32x4;

// ws layout (bytes):
//   vsb  [NV][32]  bf16 : 0          (2,048,000)
//   vstb [32][NV]  bf16 : 2,048,000  (2,048,000)
//   Fb   [M][32]   bf16 : 4,096,000  (262,144)
//   part [1024][1056] f32 : 4,358,144 (4,325,376)
//   cnt  [64] int       : 8,683,520
#define OFF_VSB  0
#define OFF_VSTB 2048000
#define OFF_FB   4096000
#define OFF_PART 4358144
#define OFF_CNT  8683520

#define NVS_BLOCKS 1000        // 32 v-rows per block
#define NF_BLOCKS  512         // MROWS*32/256

static __device__ __forceinline__ unsigned pkbf(float lo, float hi) {
    union { __hip_bfloat162 h; unsigned u; } cv;
    cv.h.x = __float2bfloat16(lo);
    cv.h.y = __float2bfloat16(hi);
    return cv.u;
}
static __device__ __forceinline__ f32x4 ntload(const float* p) {
    return __builtin_nontemporal_load((const f32x4*)p);
}

// ---------------- prep: vs sums (bf16 + transpose, coalesced) AND scaled F ----------------
__global__ __launch_bounds__(256)
void prep_kernel(const float* __restrict__ emb,
                 const float* __restrict__ x, const float* __restrict__ W,
                 const float* __restrict__ bias, const float* __restrict__ temps,
                 unsigned short* __restrict__ vsb,
                 unsigned short* __restrict__ vstb,
                 unsigned short* __restrict__ Fb,
                 int* __restrict__ cnt) {
    const int blk = blockIdx.x;
    const int tid = threadIdx.x;
    if (blk == 0 && tid < 64) cnt[tid] = 0;   // reset finish counters every launch
    if (blk < NVS_BLOCKS) {
        const int vbase = blk * 32;
        const int wave = tid >> 6, lane = tid & 63;
        __shared__ float lds[32][33];
        // wave handles v-rows vl = wave, wave+4, ... (8 rows); 4KB coalesced read per row
        for (int vl = wave; vl < 32; vl += 4) {
            const float* p = emb + (size_t)(vbase + vl) * 1024 + lane * 4;
            f32x4 a0 = ntload(p), a1 = ntload(p + 256), a2 = ntload(p + 512), a3 = ntload(p + 768);
            float s0 = a0.x + a0.y + a0.z + a0.w;
            float s1 = a1.x + a1.y + a1.z + a1.w;
            float s2 = a2.x + a2.y + a2.z + a2.w;
            float s3 = a3.x + a3.y + a3.z + a3.w;
            // reduce over lanes within 8-lane groups (same h = lane>>3)
            s0 += __shfl_xor(s0, 1, 64); s0 += __shfl_xor(s0, 2, 64); s0 += __shfl_xor(s0, 4, 64);
            s1 += __shfl_xor(s1, 1, 64); s1 += __shfl_xor(s1, 2, 64); s1 += __shfl_xor(s1, 4, 64);
            s2 += __shfl_xor(s2, 1, 64); s2 += __shfl_xor(s2, 2, 64); s2 += __shfl_xor(s2, 4, 64);
            s3 += __shfl_xor(s3, 1, 64); s3 += __shfl_xor(s3, 2, 64); s3 += __shfl_xor(s3, 4, 64);
            if ((lane & 7) == 0) {
                int hb = lane >> 3;
                lds[vl][hb]      = s0;
                lds[vl][hb + 8]  = s1;
                lds[vl][hb + 16] = s2;
                lds[vl][hb + 24] = s3;
            }
        }
        __syncthreads();
        // vsb: thread writes 4 shorts (8B): v=tid>>3, h=(tid&7)*4
        {
            int v = tid >> 3, h = (tid & 7) * 4;
            unsigned o[2];
            o[0] = pkbf(lds[v][h],     lds[v][h + 1]);
            o[1] = pkbf(lds[v][h + 2], lds[v][h + 3]);
            *(uint2*)(vsb + (size_t)(vbase + v) * 32 + h) = *(uint2*)o;
        }
        // vstb: thread writes 4 shorts (8B) of row h: h = tid>>3, vi=(tid&7)*4
        {
            int h = tid >> 3, vi = (tid & 7) * 4;
            unsigned o[2];
            o[0] = pkbf(lds[vi][h],     lds[vi + 1][h]);
            o[1] = pkbf(lds[vi + 2][h], lds[vi + 3][h]);
            *(uint2*)(vstb + (size_t)h * NV + vbase + vi) = *(uint2*)o;
        }
    } else {
        int t = (blk - NVS_BLOCKS) * 256 + tid;   // t = frow*32 + d
        int frow = t >> 5, d = t & 31;
        const float4* xp = (const float4*)(x + (size_t)frow * 32);
        const float4* wp = (const float4*)(W + (size_t)d * 32);
        float s = bias[d];
#pragma unroll
        for (int i = 0; i < 8; ++i) {
            float4 xv = xp[i];
            float4 wv = wp[i];
            s += xv.x * wv.x + xv.y * wv.y + xv.z * wv.z + xv.w * wv.w;
        }
        // fold 1/temp and log2(e) into F so inner loop is bare exp2
        float sc = 1.44269504088896f / fmaxf(temps[frow & 31], 0.1f);
        __hip_bfloat16 bv = __float2bfloat16(s * sc);
        Fb[t] = *reinterpret_cast<unsigned short*>(&bv);
    }
}

// ---------------- fused MFMA flash kernel: 2 q-tiles/block, pipelined, self-finishing ----------------
// b = qp*8 + s. Block owns q-rows [qp*64, qp*64+64), slice s (chunks [125s,125s+125)).
// Swapped QK^T: D[v][q] -> lane(hi,c): q=c, v=(r&3)+8*(r>>2)+4*hi.
// permlane32_swap builds PV A-frags; lsum via mfma(P, ones).
// Last of 8 slice-blocks per qp combines partials and writes out (atomic counter).

#define LOADCH(VA0, VA1, VB0, VB1, CH) do {                                        \
    const unsigned short* _vr = vsb + ((size_t)(CH) << 10) + (c << 5) + (hi << 3); \
    VA0 = *(const short8*)(_vr);                                                   \
    VA1 = *(const short8*)(_vr + 16);                                              \
    const unsigned short* _vt = vstb + (size_t)c * NV + ((CH) << 5) + (hi << 3);   \
    VB0 = *(const short8*)(_vt);                                                   \
    VB1 = *(const short8*)(_vt + 16);                                              \
} while (0)

#define TILE(QA, QB, OACC, LACC, VA0, VA1, VB0, VB1) do {                          \
    f32x16 sa = __builtin_amdgcn_mfma_f32_32x32x16_bf16(VA0, QA, fz, 0, 0, 0);     \
    sa = __builtin_amdgcn_mfma_f32_32x32x16_bf16(VA1, QB, sa, 0, 0, 0);            \
    float w[16];                                                                   \
    _Pragma("unroll")                                                              \
    for (int r = 0; r < 16; ++r) w[r] = __builtin_amdgcn_exp2f(sa[r]);             \
    unsigned u0 = pkbf(w[0], w[1]),   u1 = pkbf(w[2], w[3]);                       \
    unsigned u2 = pkbf(w[4], w[5]),   u3 = pkbf(w[6], w[7]);                       \
    unsigned u4 = pkbf(w[8], w[9]),   u5 = pkbf(w[10], w[11]);                     \
    unsigned u6 = pkbf(w[12], w[13]), u7 = pkbf(w[14], w[15]);                     \
    asm volatile("v_permlane32_swap_b32 %0, %1" : "+v"(u0), "+v"(u2));             \
    asm volatile("v_permlane32_swap_b32 %0, %1" : "+v"(u1), "+v"(u3));             \
    asm volatile("v_permlane32_swap_b32 %0, %1" : "+v"(u4), "+v"(u6));             \
    asm volatile("v_permlane32_swap_b32 %0, %1" : "+v"(u5), "+v"(u7));             \
    union { unsigned u[4]; short8 v8; } pa0, pa1;                                  \
    pa0.u[0] = u0; pa0.u[1] = u1; pa0.u[2] = u2; pa0.u[3] = u3;                    \
    pa1.u[0] = u4; pa1.u[1] = u5; pa1.u[2] = u6; pa1.u[3] = u7;                    \
    OACC = __builtin_amdgcn_mfma_f32_32x32x16_bf16(pa0.v8, VB0, OACC, 0, 0, 0);    \
    OACC = __builtin_amdgcn_mfma_f32_32x32x16_bf16(pa1.v8, VB1, OACC, 0, 0, 0);    \
    LACC = __builtin_amdgcn_mfma_f32_32x32x16_bf16(pa0.v8, onesv, LACC, 0, 0, 0);  \
    LACC = __builtin_amdgcn_mfma_f32_32x32x16_bf16(pa1.v8, onesv, LACC, 0, 0, 0);  \
} while (0)

#define COMPUTE(VA0, VA1, VB0, VB1) do {                                           \
    TILE(q0a, q0b, oacc0, lacc0, VA0, VA1, VB0, VB1);                              \
    TILE(q1a, q1b, oacc1, lacc1, VA0, VA1, VB0, VB1);                              \
} while (0)

__global__ __launch_bounds__(256, 2)
void fused_mfma(const unsigned short* __restrict__ vsb,
                const unsigned short* __restrict__ vstb,
                const unsigned short* __restrict__ Fb,
                float* __restrict__ part, int* __restrict__ cnt,
                float* __restrict__ out) {
    const int b = blockIdx.x;
    const int s = b & 7;
    const int qp = b >> 3;
    const int tid = threadIdx.x;
    const int wave = tid >> 6, lane = tid & 63;
    const int hi = lane >> 5, c = lane & 31;

    const int qrow0 = qp * 64 + c;
    short8 q0a = *(const short8*)(Fb + (size_t)qrow0 * 32 + 8 * hi);
    short8 q0b = *(const short8*)(Fb + (size_t)qrow0 * 32 + 16 + 8 * hi);
    short8 q1a = *(const short8*)(Fb + (size_t)(qrow0 + 32) * 32 + 8 * hi);
    short8 q1b = *(const short8*)(Fb + (size_t)(qrow0 + 32) * 32 + 16 + 8 * hi);

    union { unsigned u[4]; short8 v8; } onesu;
    onesu.u[0] = 0x3F803F80u; onesu.u[1] = 0x3F803F80u;
    onesu.u[2] = 0x3F803F80u; onesu.u[3] = 0x3F803F80u;
    const short8 onesv = onesu.v8;

    f32x16 fz, oacc0, oacc1, lacc0, lacc1;
#pragma unroll
    for (int r = 0; r < 16; ++r) { fz[r] = 0.f; oacc0[r] = 0.f; oacc1[r] = 0.f; lacc0[r] = 0.f; lacc1[r] = 0.f; }

    // software-pipelined chunk loop: wave's chunks ch0, ch0+4, ... (31 or 32 of them)
    const int n = (CHUNKS_PER_SLICE - wave + 3) >> 2;
    int ch = s * CHUNKS_PER_SLICE + wave;
    short8 a0, a1, a2, a3, b0, b1, b2, b3;
    LOADCH(a0, a1, a2, a3, ch);
    int i = 1;
    for (; i + 1 < n; i += 2) {
        LOADCH(b0, b1, b2, b3, ch + 4);
        COMPUTE(a0, a1, a2, a3);
        LOADCH(a0, a1, a2, a3, ch + 8);
        COMPUTE(b0, b1, b2, b3);
        ch += 8;
    }
    if (i < n) {
        LOADCH(b0, b1, b2, b3, ch + 4);
        COMPUTE(a0, a1, a2, a3);
        COMPUTE(b0, b1, b2, b3);
    } else {
        COMPUTE(a0, a1, a2, a3);
    }

    // cross-wave reduce in LDS (both tiles), then write block partials
    __shared__ float red[2][4][64 * 17];   // stride 17: bank-conflict-free
    __shared__ float lred[2][4][32];
    {
        float* rw0 = &red[0][wave][lane * 17];
        float* rw1 = &red[1][wave][lane * 17];
#pragma unroll
        for (int r = 0; r < 16; ++r) { rw0[r] = oacc0[r]; rw1[r] = oacc1[r]; }
        if (c == 0) {
#pragma unroll
            for (int r = 0; r < 16; ++r) {
                int q = (r & 3) + 8 * (r >> 2) + 4 * hi;
                lred[0][wave][q] = lacc0[r];
                lred[1][wave][q] = lacc1[r];
            }
        }
    }
    __syncthreads();

#pragma unroll
    for (int t = 0; t < 2; ++t) {
        const size_t pbase = (size_t)((qp * 2 + t) * NSLICE + s) * PART_STRIDE;
        for (int idx = tid; idx < 1024; idx += 256) {
            int ln = idx >> 4, r = idx & 15;
            float sum = red[t][0][ln * 17 + r] + red[t][1][ln * 17 + r]
                      + red[t][2][ln * 17 + r] + red[t][3][ln * 17 + r];
            int lhi = ln >> 5, lc = ln & 31;
            int q = (r & 3) + 8 * (r >> 2) + 4 * lhi;
            part[pbase + (q << 5) + lc] = sum;
        }
        if (tid < 32)
            part[pbase + 1024 + tid] = lred[t][0][tid] + lred[t][1][tid]
                                     + lred[t][2][tid] + lred[t][3][tid];
    }

    // last of the 8 slice-blocks for this qp combines and writes the output
    __threadfence();
    __syncthreads();
    __shared__ int sdone;
    if (tid == 0) sdone = (atomicAdd(&cnt[qp], 1) == NSLICE - 1) ? 1 : 0;
    __syncthreads();
    if (sdone) {
        __threadfence();
        for (int t2 = tid; t2 < 2048; t2 += 256) {
            int lr = t2 >> 5, j = t2 & 31;
            int qt = qp * 2 + (lr >> 5), qi = lr & 31;
            float a = 0.f, l = 0.f;
#pragma unroll
            for (int sl = 0; sl < NSLICE; ++sl) {
                const float* p = part + (size_t)(qt * NSLICE + sl) * PART_STRIDE;
                a += p[(qi << 5) + j];
                l += p[1024 + qi];
            }
            out[(size_t)qp * 2048 + t2] = a / l;
        }
    }
}

extern "C" void kernel_launch(void* const* d_in, const int* in_sizes, int n_in,
                              void* d_out, int out_size, void* d_ws, size_t ws_size,
                              hipStream_t stream) {
    const float* x     = (const float*)d_in[0];
    const float* W     = (const float*)d_in[1];
    const float* bias  = (const float*)d_in[2];
    const float* temps = (const float*)d_in[3];
    const float* emb   = (const float*)d_in[4];
    float* out = (float*)d_out;

    char* ws = (char*)d_ws;
    unsigned short* vsb  = (unsigned short*)(ws + OFF_VSB);
    unsigned short* vstb = (unsigned short*)(ws + OFF_VSTB);
    unsigned short* Fb   = (unsigned short*)(ws + OFF_FB);
    float*          part = (float*)(ws + OFF_PART);
    int*            cnt  = (int*)(ws + OFF_CNT);

    prep_kernel<<<NVS_BLOCKS + NF_BLOCKS, 256, 0, stream>>>(emb, x, W, bias, temps,
                                                            vsb, vstb, Fb, cnt);
    fused_mfma<<<64 * NSLICE, 256, 0, stream>>>(vsb, vstb, Fb, part, cnt, out);
}

// Round 8
// 62.335 us; speedup vs baseline: 2.3530x; 2.3530x over previous
//
#include <hip/hip_runtime.h>
#include <hip/hip_bf16.h>

// B=2,T=64,V=32000,NH=32,HD=32. BT=128, M=4096 rows, D=32.
// Flash-attn formulation: Q=F (4096x32, pre-scaled by invt*log2e),
// K=V=vs (32000x32). S=Q.vs^T, P=exp2(S), out = P.vs / rowsum(P).
#define NV      32000
#define MROWS   4096
#define NSLICE  8
#define CHUNKS_PER_SLICE 125   // of 1000 total 32-v chunks
#define PART_STRIDE 1056       // 32x32 acc + 32 lsum

typedef __attribute__((ext_vector_type(8))) short short8;
typedef __attribute__((ext_vector_type(16))) float f32x16;
typedef __attribute__((ext_vector_type(4))) float f32x4;

// ws layout (bytes):
//   vsb  [NV][32]  bf16 : 0          (2,048,000)
//   vstb [32][NV]  bf16 : 2,048,000  (2,048,000)
//   Fb   [M][32]   bf16 : 4,096,000  (262,144)
//   part [1024][1056] f32 : 4,358,144 (4,325,376)  total ~8.7 MB
#define OFF_VSB  0
#define OFF_VSTB 2048000
#define OFF_FB   4096000
#define OFF_PART 4358144

#define NVS_BLOCKS 1000        // 32 v-rows per block
#define NF_BLOCKS  512         // MROWS*32/256

static __device__ __forceinline__ unsigned pkbf(float lo, float hi) {
    union { __hip_bfloat162 h; unsigned u; } cv;
    cv.h.x = __float2bfloat16(lo);
    cv.h.y = __float2bfloat16(hi);
    return cv.u;
}
static __device__ __forceinline__ f32x4 ntload(const float* p) {
    return __builtin_nontemporal_load((const f32x4*)p);
}

// ---------------- prep: vs sums (bf16 + transpose, coalesced) AND scaled F ----------------
__global__ __launch_bounds__(256)
void prep_kernel(const float* __restrict__ emb,
                 const float* __restrict__ x, const float* __restrict__ W,
                 const float* __restrict__ bias, const float* __restrict__ temps,
                 unsigned short* __restrict__ vsb,
                 unsigned short* __restrict__ vstb,
                 unsigned short* __restrict__ Fb) {
    const int blk = blockIdx.x;
    const int tid = threadIdx.x;
    if (blk < NVS_BLOCKS) {
        const int vbase = blk * 32;
        const int wave = tid >> 6, lane = tid & 63;
        __shared__ float lds[32][33];
        // wave handles v-rows vl = wave, wave+4, ... (8 rows); 4KB coalesced read per row
        for (int vl = wave; vl < 32; vl += 4) {
            const float* p = emb + (size_t)(vbase + vl) * 1024 + lane * 4;
            f32x4 a0 = ntload(p), a1 = ntload(p + 256), a2 = ntload(p + 512), a3 = ntload(p + 768);
            float s0 = a0.x + a0.y + a0.z + a0.w;
            float s1 = a1.x + a1.y + a1.z + a1.w;
            float s2 = a2.x + a2.y + a2.z + a2.w;
            float s3 = a3.x + a3.y + a3.z + a3.w;
            // reduce over lanes within 8-lane groups (same h = lane>>3)
            s0 += __shfl_xor(s0, 1, 64); s0 += __shfl_xor(s0, 2, 64); s0 += __shfl_xor(s0, 4, 64);
            s1 += __shfl_xor(s1, 1, 64); s1 += __shfl_xor(s1, 2, 64); s1 += __shfl_xor(s1, 4, 64);
            s2 += __shfl_xor(s2, 1, 64); s2 += __shfl_xor(s2, 2, 64); s2 += __shfl_xor(s2, 4, 64);
            s3 += __shfl_xor(s3, 1, 64); s3 += __shfl_xor(s3, 2, 64); s3 += __shfl_xor(s3, 4, 64);
            if ((lane & 7) == 0) {
                int hb = lane >> 3;
                lds[vl][hb]      = s0;
                lds[vl][hb + 8]  = s1;
                lds[vl][hb + 16] = s2;
                lds[vl][hb + 24] = s3;
            }
        }
        __syncthreads();
        // vsb: thread writes 4 shorts (8B): v=tid>>3, h=(tid&7)*4
        {
            int v = tid >> 3, h = (tid & 7) * 4;
            unsigned o[2];
            o[0] = pkbf(lds[v][h],     lds[v][h + 1]);
            o[1] = pkbf(lds[v][h + 2], lds[v][h + 3]);
            *(uint2*)(vsb + (size_t)(vbase + v) * 32 + h) = *(uint2*)o;
        }
        // vstb: thread writes 4 shorts (8B) of row h: h = tid>>3, vi=(tid&7)*4
        {
            int h = tid >> 3, vi = (tid & 7) * 4;
            unsigned o[2];
            o[0] = pkbf(lds[vi][h],     lds[vi + 1][h]);
            o[1] = pkbf(lds[vi + 2][h], lds[vi + 3][h]);
            *(uint2*)(vstb + (size_t)h * NV + vbase + vi) = *(uint2*)o;
        }
    } else {
        int t = (blk - NVS_BLOCKS) * 256 + tid;   // t = frow*32 + d
        int frow = t >> 5, d = t & 31;
        const float4* xp = (const float4*)(x + (size_t)frow * 32);
        const float4* wp = (const float4*)(W + (size_t)d * 32);
        float s = bias[d];
#pragma unroll
        for (int i = 0; i < 8; ++i) {
            float4 xv = xp[i];
            float4 wv = wp[i];
            s += xv.x * wv.x + xv.y * wv.y + xv.z * wv.z + xv.w * wv.w;
        }
        // fold 1/temp and log2(e) into F so inner loop is bare exp2
        float sc = 1.44269504088896f / fmaxf(temps[frow & 31], 0.1f);
        __hip_bfloat16 bv = __float2bfloat16(s * sc);
        Fb[t] = *reinterpret_cast<unsigned short*>(&bv);
    }
}

// ---------------- fused MFMA flash kernel: 2 q-tiles per block ----------------
// b = qp*8 + s (s = b&7 -> XCD-local 1MB slice). Block owns q-rows [qp*64, qp*64+64),
// tiles qt0=2qp, qt1=2qp+1, sharing every vs/vst chunk read. 4 waves interleave chunks.
// Swapped QK^T: D[v][q] -> lane(hi,c): q=c, v=(r&3)+8*(r>>2)+4*hi.
// permlane32_swap builds PV A-frags; lsum via mfma(P, ones).
// NOTE (round-7 lesson): register budget here is saturated at the (256,2) cap;
// do NOT add live state (staging regs, extra accumulators) to this loop.
__global__ __launch_bounds__(256, 2)
void fused_mfma(const unsigned short* __restrict__ vsb,
                const unsigned short* __restrict__ vstb,
                const unsigned short* __restrict__ Fb,
                float* __restrict__ part) {
    const int b = blockIdx.x;
    const int s = b & 7;
    const int qp = b >> 3;
    const int tid = threadIdx.x;
    const int wave = tid >> 6, lane = tid & 63;
    const int hi = lane >> 5, c = lane & 31;

    const int qrow0 = qp * 64 + c;
    short8 q0a = *(const short8*)(Fb + (size_t)qrow0 * 32 + 8 * hi);
    short8 q0b = *(const short8*)(Fb + (size_t)qrow0 * 32 + 16 + 8 * hi);
    short8 q1a = *(const short8*)(Fb + (size_t)(qrow0 + 32) * 32 + 8 * hi);
    short8 q1b = *(const short8*)(Fb + (size_t)(qrow0 + 32) * 32 + 16 + 8 * hi);

    union { unsigned u[4]; short8 v8; } onesb;
    onesb.u[0] = 0x3F803F80u; onesb.u[1] = 0x3F803F80u;
    onesb.u[2] = 0x3F803F80u; onesb.u[3] = 0x3F803F80u;

    f32x16 oacc0, oacc1, lacc0, lacc1;
#pragma unroll
    for (int r = 0; r < 16; ++r) { oacc0[r] = 0.f; oacc1[r] = 0.f; lacc0[r] = 0.f; lacc1[r] = 0.f; }

    for (int ch = s * CHUNKS_PER_SLICE + wave; ch < (s + 1) * CHUNKS_PER_SLICE; ch += 4) {
        const int vbase = ch * 32;
        const unsigned short* vrow = vsb + (size_t)(vbase + c) * 32 + 8 * hi;
        short8 va0 = *(const short8*)(vrow);
        short8 va1 = *(const short8*)(vrow + 16);
        const unsigned short* vtrow = vstb + (size_t)c * NV + vbase + 8 * hi;
        short8 vb0 = *(const short8*)(vtrow);
        short8 vb1 = *(const short8*)(vtrow + 16);

#pragma unroll
        for (int t = 0; t < 2; ++t) {
            f32x16 sa;
#pragma unroll
            for (int r = 0; r < 16; ++r) sa[r] = 0.f;
            sa = __builtin_amdgcn_mfma_f32_32x32x16_bf16(va0, t ? q1a : q0a, sa, 0, 0, 0);
            sa = __builtin_amdgcn_mfma_f32_32x32x16_bf16(va1, t ? q1b : q0b, sa, 0, 0, 0);

            float w[16];
#pragma unroll
            for (int r = 0; r < 16; ++r) w[r] = __builtin_amdgcn_exp2f(sa[r]);

            unsigned u0 = pkbf(w[0], w[1]),   u1 = pkbf(w[2], w[3]);
            unsigned u2 = pkbf(w[4], w[5]),   u3 = pkbf(w[6], w[7]);
            unsigned u4 = pkbf(w[8], w[9]),   u5 = pkbf(w[10], w[11]);
            unsigned u6 = pkbf(w[12], w[13]), u7 = pkbf(w[14], w[15]);
            asm volatile("v_permlane32_swap_b32 %0, %1" : "+v"(u0), "+v"(u2));
            asm volatile("v_permlane32_swap_b32 %0, %1" : "+v"(u1), "+v"(u3));
            asm volatile("v_permlane32_swap_b32 %0, %1" : "+v"(u4), "+v"(u6));
            asm volatile("v_permlane32_swap_b32 %0, %1" : "+v"(u5), "+v"(u7));

            union { unsigned u[4]; short8 v8; } pa0, pa1;
            pa0.u[0] = u0; pa0.u[1] = u1; pa0.u[2] = u2; pa0.u[3] = u3;
            pa1.u[0] = u4; pa1.u[1] = u5; pa1.u[2] = u6; pa1.u[3] = u7;

            if (t == 0) {
                oacc0 = __builtin_amdgcn_mfma_f32_32x32x16_bf16(pa0.v8, vb0, oacc0, 0, 0, 0);
                oacc0 = __builtin_amdgcn_mfma_f32_32x32x16_bf16(pa1.v8, vb1, oacc0, 0, 0, 0);
                lacc0 = __builtin_amdgcn_mfma_f32_32x32x16_bf16(pa0.v8, onesb.v8, lacc0, 0, 0, 0);
                lacc0 = __builtin_amdgcn_mfma_f32_32x32x16_bf16(pa1.v8, onesb.v8, lacc0, 0, 0, 0);
            } else {
                oacc1 = __builtin_amdgcn_mfma_f32_32x32x16_bf16(pa0.v8, vb0, oacc1, 0, 0, 0);
                oacc1 = __builtin_amdgcn_mfma_f32_32x32x16_bf16(pa1.v8, vb1, oacc1, 0, 0, 0);
                lacc1 = __builtin_amdgcn_mfma_f32_32x32x16_bf16(pa0.v8, onesb.v8, lacc1, 0, 0, 0);
                lacc1 = __builtin_amdgcn_mfma_f32_32x32x16_bf16(pa1.v8, onesb.v8, lacc1, 0, 0, 0);
            }
        }
    }

    // cross-wave reduce in LDS (both tiles), then write block partials
    __shared__ float red[2][4][64 * 17];   // stride 17: bank-conflict-free
    __shared__ float lred[2][4][32];
    {
        float* rw0 = &red[0][wave][lane * 17];
        float* rw1 = &red[1][wave][lane * 17];
#pragma unroll
        for (int r = 0; r < 16; ++r) { rw0[r] = oacc0[r]; rw1[r] = oacc1[r]; }
        if (c == 0) {
#pragma unroll
            for (int r = 0; r < 16; ++r) {
                int q = (r & 3) + 8 * (r >> 2) + 4 * hi;
                lred[0][wave][q] = lacc0[r];
                lred[1][wave][q] = lacc1[r];
            }
        }
    }
    __syncthreads();

#pragma unroll
    for (int t = 0; t < 2; ++t) {
        const size_t pbase = (size_t)((qp * 2 + t) * NSLICE + s) * PART_STRIDE;
        for (int idx = tid; idx < 1024; idx += 256) {
            int ln = idx >> 4, r = idx & 15;
            float sum = red[t][0][ln * 17 + r] + red[t][1][ln * 17 + r]
                      + red[t][2][ln * 17 + r] + red[t][3][ln * 17 + r];
            int lhi = ln >> 5, lc = ln & 31;
            int q = (r & 3) + 8 * (r >> 2) + 4 * lhi;
            part[pbase + (q << 5) + lc] = sum;
        }
        if (tid < 32)
            part[pbase + 1024 + tid] = lred[t][0][tid] + lred[t][1][tid]
                                     + lred[t][2][tid] + lred[t][3][tid];
    }
}

// ---------------- combine slice partials ----------------
__global__ void combine_kernel(const float* __restrict__ part, float* __restrict__ out) {
    int t = blockIdx.x * 256 + threadIdx.x;      // t = qrow*32 + j
    if (t >= MROWS * 32) return;
    int qrow = t >> 5, j = t & 31;
    int qt = qrow >> 5, qi = qrow & 31;
    float a = 0.f, l = 0.f;
#pragma unroll
    for (int s = 0; s < NSLICE; ++s) {
        const float* p = part + (size_t)(qt * NSLICE + s) * PART_STRIDE;
        a += p[(qi << 5) + j];
        l += p[1024 + qi];
    }
    out[t] = a / l;
}

extern "C" void kernel_launch(void* const* d_in, const int* in_sizes, int n_in,
                              void* d_out, int out_size, void* d_ws, size_t ws_size,
                              hipStream_t stream) {
    const float* x     = (const float*)d_in[0];
    const float* W     = (const float*)d_in[1];
    const float* bias  = (const float*)d_in[2];
    const float* temps = (const float*)d_in[3];
    const float* emb   = (const float*)d_in[4];
    float* out = (float*)d_out;

    char* ws = (char*)d_ws;
    unsigned short* vsb  = (unsigned short*)(ws + OFF_VSB);
    unsigned short* vstb = (unsigned short*)(ws + OFF_VSTB);
    unsigned short* Fb   = (unsigned short*)(ws + OFF_FB);
    float*          part = (float*)(ws + OFF_PART);

    prep_kernel<<<NVS_BLOCKS + NF_BLOCKS, 256, 0, stream>>>(emb, x, W, bias, temps,
                                                            vsb, vstb, Fb);
    fused_mfma<<<64 * NSLICE, 256, 0, stream>>>(vsb, vstb, Fb, part);
    combine_kernel<<<(MROWS * 32 + 255) / 256, 256, 0, stream>>>(part, out);
}

// Round 9
// 62.109 us; speedup vs baseline: 2.3616x; 1.0036x over previous
//
#include <hip/hip_runtime.h>
#include <hip/hip_bf16.h>

// B=2,T=64,V=32000,NH=32,HD=32. BT=128, M=4096 rows, D=32.
// Flash-attn formulation: Q=F (4096x32, pre-scaled by invt*log2e),
// K=V=vs (32000x32). S=Q.vs^T, P=exp2(S), out = P.vs / rowsum(P).
#define NV      32000
#define MROWS   4096
#define NSLICE  16             // 1024 blocks -> 4/CU -> 4 waves/SIMD
#define PART_STRIDE 1056       // 32x32 acc + 32 lsum

typedef __attribute__((ext_vector_type(8))) short short8;
typedef __attribute__((ext_vector_type(16))) float f32x16;
typedef __attribute__((ext_vector_type(4))) float f32x4;

// ws layout (bytes):
//   vsb  [NV][32]  bf16 : 0          (2,048,000)
//   vstb [32][NV]  bf16 : 2,048,000  (2,048,000)
//   Fb   [M][32]   bf16 : 4,096,000  (262,144)
//   part [2048][1056] f32 : 4,358,144 (8,650,752)  total ~13 MB (ws ~512MB)
#define OFF_VSB  0
#define OFF_VSTB 2048000
#define OFF_FB   4096000
#define OFF_PART 4358144

#define NVS_BLOCKS 1000        // 32 v-rows per block
#define NF_BLOCKS  512         // MROWS*32/256

static __device__ __forceinline__ unsigned pkbf(float lo, float hi) {
    union { __hip_bfloat162 h; unsigned u; } cv;
    cv.h.x = __float2bfloat16(lo);
    cv.h.y = __float2bfloat16(hi);
    return cv.u;
}
static __device__ __forceinline__ f32x4 ntload(const float* p) {
    return __builtin_nontemporal_load((const f32x4*)p);
}

// ---------------- prep: vs sums (bf16 + transpose, coalesced) AND scaled F ----------------
__global__ __launch_bounds__(256)
void prep_kernel(const float* __restrict__ emb,
                 const float* __restrict__ x, const float* __restrict__ W,
                 const float* __restrict__ bias, const float* __restrict__ temps,
                 unsigned short* __restrict__ vsb,
                 unsigned short* __restrict__ vstb,
                 unsigned short* __restrict__ Fb) {
    const int blk = blockIdx.x;
    const int tid = threadIdx.x;
    if (blk < NVS_BLOCKS) {
        const int vbase = blk * 32;
        const int wave = tid >> 6, lane = tid & 63;
        __shared__ float lds[32][33];
        // wave handles v-rows vl = wave, wave+4, ... (8 rows); 4KB coalesced read per row
        for (int vl = wave; vl < 32; vl += 4) {
            const float* p = emb + (size_t)(vbase + vl) * 1024 + lane * 4;
            f32x4 a0 = ntload(p), a1 = ntload(p + 256), a2 = ntload(p + 512), a3 = ntload(p + 768);
            float s0 = a0.x + a0.y + a0.z + a0.w;
            float s1 = a1.x + a1.y + a1.z + a1.w;
            float s2 = a2.x + a2.y + a2.z + a2.w;
            float s3 = a3.x + a3.y + a3.z + a3.w;
            // reduce over lanes within 8-lane groups (same h = lane>>3)
            s0 += __shfl_xor(s0, 1, 64); s0 += __shfl_xor(s0, 2, 64); s0 += __shfl_xor(s0, 4, 64);
            s1 += __shfl_xor(s1, 1, 64); s1 += __shfl_xor(s1, 2, 64); s1 += __shfl_xor(s1, 4, 64);
            s2 += __shfl_xor(s2, 1, 64); s2 += __shfl_xor(s2, 2, 64); s2 += __shfl_xor(s2, 4, 64);
            s3 += __shfl_xor(s3, 1, 64); s3 += __shfl_xor(s3, 2, 64); s3 += __shfl_xor(s3, 4, 64);
            if ((lane & 7) == 0) {
                int hb = lane >> 3;
                lds[vl][hb]      = s0;
                lds[vl][hb + 8]  = s1;
                lds[vl][hb + 16] = s2;
                lds[vl][hb + 24] = s3;
            }
        }
        __syncthreads();
        // vsb: thread writes 4 shorts (8B): v=tid>>3, h=(tid&7)*4
        {
            int v = tid >> 3, h = (tid & 7) * 4;
            unsigned o[2];
            o[0] = pkbf(lds[v][h],     lds[v][h + 1]);
            o[1] = pkbf(lds[v][h + 2], lds[v][h + 3]);
            *(uint2*)(vsb + (size_t)(vbase + v) * 32 + h) = *(uint2*)o;
        }
        // vstb: thread writes 4 shorts (8B) of row h: h = tid>>3, vi=(tid&7)*4
        {
            int h = tid >> 3, vi = (tid & 7) * 4;
            unsigned o[2];
            o[0] = pkbf(lds[vi][h],     lds[vi + 1][h]);
            o[1] = pkbf(lds[vi + 2][h], lds[vi + 3][h]);
            *(uint2*)(vstb + (size_t)h * NV + vbase + vi) = *(uint2*)o;
        }
    } else {
        int t = (blk - NVS_BLOCKS) * 256 + tid;   // t = frow*32 + d
        int frow = t >> 5, d = t & 31;
        const float4* xp = (const float4*)(x + (size_t)frow * 32);
        const float4* wp = (const float4*)(W + (size_t)d * 32);
        float s = bias[d];
#pragma unroll
        for (int i = 0; i < 8; ++i) {
            float4 xv = xp[i];
            float4 wv = wp[i];
            s += xv.x * wv.x + xv.y * wv.y + xv.z * wv.z + xv.w * wv.w;
        }
        // fold 1/temp and log2(e) into F so inner loop is bare exp2
        float sc = 1.44269504088896f / fmaxf(temps[frow & 31], 0.1f);
        __hip_bfloat16 bv = __float2bfloat16(s * sc);
        Fb[t] = *reinterpret_cast<unsigned short*>(&bv);
    }
}

// ---------------- fused MFMA flash kernel: 2 q-tiles/block, 4 waves/SIMD ----------------
// b: s = b&15 (slice, 62-63 chunks; all 64 blocks of slice s land on XCD s&7 ->
// slice L2-resident), qp = b>>4 (q-rows [qp*64, qp*64+64)).
// Swapped QK^T: D[v][q] -> lane(hi,c): q=c, v=(r&3)+8*(r>>2)+4*hi.
// permlane32_swap builds PV A-frags; lsum via VALU pairwise tree (no lacc ->
// state fits the 128-VGPR cap of __launch_bounds__(256,4); round-7 lesson:
// do NOT add live state to this loop).
#define TILE(QA, QB, OACC, LSUM) do {                                              \
    f32x16 sa;                                                                     \
    _Pragma("unroll")                                                              \
    for (int r = 0; r < 16; ++r) sa[r] = 0.f;                                      \
    sa = __builtin_amdgcn_mfma_f32_32x32x16_bf16(va0, QA, sa, 0, 0, 0);            \
    sa = __builtin_amdgcn_mfma_f32_32x32x16_bf16(va1, QB, sa, 0, 0, 0);            \
    _Pragma("unroll")                                                              \
    for (int r = 0; r < 16; ++r) sa[r] = __builtin_amdgcn_exp2f(sa[r]);            \
    {                                                                              \
        float t0 = sa[0] + sa[1],   t1 = sa[2] + sa[3];                            \
        float t2 = sa[4] + sa[5],   t3 = sa[6] + sa[7];                            \
        float t4 = sa[8] + sa[9],   t5 = sa[10] + sa[11];                          \
        float t6 = sa[12] + sa[13], t7 = sa[14] + sa[15];                          \
        LSUM += ((t0 + t1) + (t2 + t3)) + ((t4 + t5) + (t6 + t7));                 \
    }                                                                              \
    unsigned u0 = pkbf(sa[0], sa[1]),   u1 = pkbf(sa[2], sa[3]);                   \
    unsigned u2 = pkbf(sa[4], sa[5]),   u3 = pkbf(sa[6], sa[7]);                   \
    unsigned u4 = pkbf(sa[8], sa[9]),   u5 = pkbf(sa[10], sa[11]);                 \
    unsigned u6 = pkbf(sa[12], sa[13]), u7 = pkbf(sa[14], sa[15]);                 \
    asm volatile("v_permlane32_swap_b32 %0, %1" : "+v"(u0), "+v"(u2));             \
    asm volatile("v_permlane32_swap_b32 %0, %1" : "+v"(u1), "+v"(u3));             \
    asm volatile("v_permlane32_swap_b32 %0, %1" : "+v"(u4), "+v"(u6));             \
    asm volatile("v_permlane32_swap_b32 %0, %1" : "+v"(u5), "+v"(u7));             \
    union { unsigned u[4]; short8 v8; } pa0, pa1;                                  \
    pa0.u[0] = u0; pa0.u[1] = u1; pa0.u[2] = u2; pa0.u[3] = u3;                    \
    pa1.u[0] = u4; pa1.u[1] = u5; pa1.u[2] = u6; pa1.u[3] = u7;                    \
    OACC = __builtin_amdgcn_mfma_f32_32x32x16_bf16(pa0.v8, vb0, OACC, 0, 0, 0);    \
    OACC = __builtin_amdgcn_mfma_f32_32x32x16_bf16(pa1.v8, vb1, OACC, 0, 0, 0);    \
} while (0)

__global__ __launch_bounds__(256, 4)
void fused_mfma(const unsigned short* __restrict__ vsb,
                const unsigned short* __restrict__ vstb,
                const unsigned short* __restrict__ Fb,
                float* __restrict__ part) {
    const int b = blockIdx.x;
    const int s = b & 15;
    const int qp = b >> 4;
    const int tid = threadIdx.x;
    const int wave = tid >> 6, lane = tid & 63;
    const int hi = lane >> 5, c = lane & 31;

    const int qrow0 = qp * 64 + c;
    short8 q0a = *(const short8*)(Fb + (size_t)qrow0 * 32 + 8 * hi);
    short8 q0b = *(const short8*)(Fb + (size_t)qrow0 * 32 + 16 + 8 * hi);
    short8 q1a = *(const short8*)(Fb + (size_t)(qrow0 + 32) * 32 + 8 * hi);
    short8 q1b = *(const short8*)(Fb + (size_t)(qrow0 + 32) * 32 + 16 + 8 * hi);

    f32x16 oacc0, oacc1;
#pragma unroll
    for (int r = 0; r < 16; ++r) { oacc0[r] = 0.f; oacc1[r] = 0.f; }
    float lsum0 = 0.f, lsum1 = 0.f;

    const int c1 = (125 * (s + 1)) >> 1;
    const unsigned short* vr_base = vsb + (c << 5) + (hi << 3);
    const unsigned short* vt_base = vstb + (size_t)c * NV + (hi << 3);

    for (int ch = ((125 * s) >> 1) + wave; ch < c1; ch += 4) {
        const unsigned short* vrow = vr_base + ((size_t)ch << 10);
        short8 va0 = *(const short8*)(vrow);
        short8 va1 = *(const short8*)(vrow + 16);
        const unsigned short* vtrow = vt_base + (ch << 5);
        short8 vb0 = *(const short8*)(vtrow);
        short8 vb1 = *(const short8*)(vtrow + 16);

        TILE(q0a, q0b, oacc0, lsum0);
        TILE(q1a, q1b, oacc1, lsum1);
    }

    // lsum: combine the two hi-halves (disjoint v-subsets per lane)
    lsum0 += __shfl_xor(lsum0, 32, 64);
    lsum1 += __shfl_xor(lsum1, 32, 64);

    // cross-wave reduce in LDS (both tiles), then write block partials
    __shared__ float red[2][4][64 * 17];   // stride 17: bank-conflict-free
    __shared__ float lred[2][4][32];
    {
        float* rw0 = &red[0][wave][lane * 17];
        float* rw1 = &red[1][wave][lane * 17];
#pragma unroll
        for (int r = 0; r < 16; ++r) { rw0[r] = oacc0[r]; rw1[r] = oacc1[r]; }
        if (hi == 0) {
            lred[0][wave][c] = lsum0;
            lred[1][wave][c] = lsum1;
        }
    }
    __syncthreads();

#pragma unroll
    for (int t = 0; t < 2; ++t) {
        const size_t pbase = (size_t)((qp * 2 + t) * NSLICE + s) * PART_STRIDE;
        for (int idx = tid; idx < 1024; idx += 256) {
            int ln = idx >> 4, r = idx & 15;
            float sum = red[t][0][ln * 17 + r] + red[t][1][ln * 17 + r]
                      + red[t][2][ln * 17 + r] + red[t][3][ln * 17 + r];
            int lhi = ln >> 5, lc = ln & 31;
            int q = (r & 3) + 8 * (r >> 2) + 4 * lhi;
            part[pbase + (q << 5) + lc] = sum;
        }
        if (tid < 32)
            part[pbase + 1024 + tid] = lred[t][0][tid] + lred[t][1][tid]
                                     + lred[t][2][tid] + lred[t][3][tid];
    }
}

// ---------------- combine slice partials ----------------
__global__ void combine_kernel(const float* __restrict__ part, float* __restrict__ out) {
    int t = blockIdx.x * 256 + threadIdx.x;      // t = qrow*32 + j
    if (t >= MROWS * 32) return;
    int qrow = t >> 5, j = t & 31;
    int qt = qrow >> 5, qi = qrow & 31;
    float a = 0.f, l = 0.f;
#pragma unroll
    for (int s = 0; s < NSLICE; ++s) {
        const float* p = part + (size_t)(qt * NSLICE + s) * PART_STRIDE;
        a += p[(qi << 5) + j];
        l += p[1024 + qi];
    }
    out[t] = a / l;
}

extern "C" void kernel_launch(void* const* d_in, const int* in_sizes, int n_in,
                              void* d_out, int out_size, void* d_ws, size_t ws_size,
                              hipStream_t stream) {
    const float* x     = (const float*)d_in[0];
    const float* W     = (const float*)d_in[1];
    const float* bias  = (const float*)d_in[2];
    const float* temps = (const float*)d_in[3];
    const float* emb   = (const float*)d_in[4];
    float* out = (float*)d_out;

    char* ws = (char*)d_ws;
    unsigned short* vsb  = (unsigned short*)(ws + OFF_VSB);
    unsigned short* vstb = (unsigned short*)(ws + OFF_VSTB);
    unsigned short* Fb   = (unsigned short*)(ws + OFF_FB);
    float*          part = (float*)(ws + OFF_PART);

    prep_kernel<<<NVS_BLOCKS + NF_BLOCKS, 256, 0, stream>>>(emb, x, W, bias, temps,
                                                            vsb, vstb, Fb);
    fused_mfma<<<64 * NSLICE, 256, 0, stream>>>(vsb, vstb, Fb, part);
    combine_kernel<<<(MROWS * 32 + 255) / 256, 256, 0, stream>>>(part, out);
}

// Round 10
// 61.020 us; speedup vs baseline: 2.4038x; 1.0179x over previous
//
#include <hip/hip_runtime.h>
#include <hip/hip_bf16.h>

// B=2,T=64,V=32000,NH=32,HD=32. BT=128, M=4096 rows, D=32.
// Flash-attn formulation: Q=F (4096x32, pre-scaled by invt*log2e),
// K=V=vs (32000x32). S=Q.vs^T, P=exp2(S), out = P.vs / rowsum(P).
#define NV      32000
#define MROWS   4096
#define NSLICE  16             // 1024 blocks -> 4/CU -> 4 waves/SIMD
#define PART_STRIDE 1056       // 32x32 acc + 32 lsum

typedef __attribute__((ext_vector_type(8))) short short8;
typedef __attribute__((ext_vector_type(16))) float f32x16;
typedef __attribute__((ext_vector_type(4))) float f32x4;

// ws layout (bytes):
//   vsb  [NV][32]        bf16 : 0          (2,048,000)
//   vstb [1000][32][32]  bf16 : 2,048,000  (2,048,000)  chunk-blocked transpose
//   Fb   [M][32]         bf16 : 4,096,000  (262,144)
//   part [2048][1056]    f32  : 4,358,144  (8,650,752)
#define OFF_VSB  0
#define OFF_VSTB 2048000
#define OFF_FB   4096000
#define OFF_PART 4358144

#define NVS_BLOCKS 1000        // 32 v-rows (one chunk) per block
#define NF_BLOCKS  512         // MROWS*32/256

static __device__ __forceinline__ unsigned pkbf(float lo, float hi) {
    union { __hip_bfloat162 h; unsigned u; } cv;
    cv.h.x = __float2bfloat16(lo);
    cv.h.y = __float2bfloat16(hi);
    return cv.u;
}
static __device__ __forceinline__ f32x4 ntload(const float* p) {
    return __builtin_nontemporal_load((const f32x4*)p);
}

// ---------------- prep: vs sums (bf16 + chunk-blocked transpose) AND scaled F ----------------
__global__ __launch_bounds__(256)
void prep_kernel(const float* __restrict__ emb,
                 const float* __restrict__ x, const float* __restrict__ W,
                 const float* __restrict__ bias, const float* __restrict__ temps,
                 unsigned short* __restrict__ vsb,
                 unsigned short* __restrict__ vstb,
                 unsigned short* __restrict__ Fb) {
    const int blk = blockIdx.x;
    const int tid = threadIdx.x;
    if (blk < NVS_BLOCKS) {
        const int vbase = blk * 32;
        const int wave = tid >> 6, lane = tid & 63;
        __shared__ float lds[32][33];
        // wave handles v-rows vl = wave, wave+4, ... (8 rows); 4KB coalesced read per row
        for (int vl = wave; vl < 32; vl += 4) {
            const float* p = emb + (size_t)(vbase + vl) * 1024 + lane * 4;
            f32x4 a0 = ntload(p), a1 = ntload(p + 256), a2 = ntload(p + 512), a3 = ntload(p + 768);
            float s0 = a0.x + a0.y + a0.z + a0.w;
            float s1 = a1.x + a1.y + a1.z + a1.w;
            float s2 = a2.x + a2.y + a2.z + a2.w;
            float s3 = a3.x + a3.y + a3.z + a3.w;
            // reduce over lanes within 8-lane groups (same h = lane>>3)
            s0 += __shfl_xor(s0, 1, 64); s0 += __shfl_xor(s0, 2, 64); s0 += __shfl_xor(s0, 4, 64);
            s1 += __shfl_xor(s1, 1, 64); s1 += __shfl_xor(s1, 2, 64); s1 += __shfl_xor(s1, 4, 64);
            s2 += __shfl_xor(s2, 1, 64); s2 += __shfl_xor(s2, 2, 64); s2 += __shfl_xor(s2, 4, 64);
            s3 += __shfl_xor(s3, 1, 64); s3 += __shfl_xor(s3, 2, 64); s3 += __shfl_xor(s3, 4, 64);
            if ((lane & 7) == 0) {
                int hb = lane >> 3;
                lds[vl][hb]      = s0;
                lds[vl][hb + 8]  = s1;
                lds[vl][hb + 16] = s2;
                lds[vl][hb + 24] = s3;
            }
        }
        __syncthreads();
        // vsb: thread writes 4 shorts (8B): v=tid>>3, h=(tid&7)*4
        {
            int v = tid >> 3, h = (tid & 7) * 4;
            unsigned o[2];
            o[0] = pkbf(lds[v][h],     lds[v][h + 1]);
            o[1] = pkbf(lds[v][h + 2], lds[v][h + 3]);
            *(uint2*)(vsb + (size_t)(vbase + v) * 32 + h) = *(uint2*)o;
        }
        // vstb (chunk-blocked): [blk][h][vi]; thread writes 4 shorts (8B):
        // h = tid>>3, vi=(tid&7)*4 -> whole block writes one contiguous 2KB tile
        {
            int h = tid >> 3, vi = (tid & 7) * 4;
            unsigned o[2];
            o[0] = pkbf(lds[vi][h],     lds[vi + 1][h]);
            o[1] = pkbf(lds[vi + 2][h], lds[vi + 3][h]);
            *(uint2*)(vstb + (size_t)blk * 1024 + h * 32 + vi) = *(uint2*)o;
        }
    } else {
        int t = (blk - NVS_BLOCKS) * 256 + tid;   // t = frow*32 + d
        int frow = t >> 5, d = t & 31;
        const float4* xp = (const float4*)(x + (size_t)frow * 32);
        const float4* wp = (const float4*)(W + (size_t)d * 32);
        float s = bias[d];
#pragma unroll
        for (int i = 0; i < 8; ++i) {
            float4 xv = xp[i];
            float4 wv = wp[i];
            s += xv.x * wv.x + xv.y * wv.y + xv.z * wv.z + xv.w * wv.w;
        }
        // fold 1/temp and log2(e) into F so inner loop is bare exp2
        float sc = 1.44269504088896f / fmaxf(temps[frow & 31], 0.1f);
        __hip_bfloat16 bv = __float2bfloat16(s * sc);
        Fb[t] = *reinterpret_cast<unsigned short*>(&bv);
    }
}

// ---------------- fused MFMA flash kernel: 2 q-tiles/block, 4 waves/SIMD ----------------
// b: s = b&15 (slice; all 64 blocks of slice s land on XCD s&7 -> slice
// L2-resident), qp = b>>4 (q-rows [qp*64, qp*64+64)).
// Swapped QK^T: D[v][q] -> lane(hi,c): q=c, v=(r&3)+8*(r>>2)+4*hi.
// permlane32_swap builds PV A-frags; lsum via VALU pairwise tree.
// PV B-frags from chunk-blocked vstb: fully coalesced (64B-stride within 2KB).
// NOTE (round-7 lesson): register budget saturated; do NOT add live state.
#define TILE(QA, QB, OACC, LSUM) do {                                              \
    f32x16 sa;                                                                     \
    _Pragma("unroll")                                                              \
    for (int r = 0; r < 16; ++r) sa[r] = 0.f;                                      \
    sa = __builtin_amdgcn_mfma_f32_32x32x16_bf16(va0, QA, sa, 0, 0, 0);            \
    sa = __builtin_amdgcn_mfma_f32_32x32x16_bf16(va1, QB, sa, 0, 0, 0);            \
    _Pragma("unroll")                                                              \
    for (int r = 0; r < 16; ++r) sa[r] = __builtin_amdgcn_exp2f(sa[r]);            \
    {                                                                              \
        float t0 = sa[0] + sa[1],   t1 = sa[2] + sa[3];                            \
        float t2 = sa[4] + sa[5],   t3 = sa[6] + sa[7];                            \
        float t4 = sa[8] + sa[9],   t5 = sa[10] + sa[11];                          \
        float t6 = sa[12] + sa[13], t7 = sa[14] + sa[15];                          \
        LSUM += ((t0 + t1) + (t2 + t3)) + ((t4 + t5) + (t6 + t7));                 \
    }                                                                              \
    unsigned u0 = pkbf(sa[0], sa[1]),   u1 = pkbf(sa[2], sa[3]);                   \
    unsigned u2 = pkbf(sa[4], sa[5]),   u3 = pkbf(sa[6], sa[7]);                   \
    unsigned u4 = pkbf(sa[8], sa[9]),   u5 = pkbf(sa[10], sa[11]);                 \
    unsigned u6 = pkbf(sa[12], sa[13]), u7 = pkbf(sa[14], sa[15]);                 \
    asm volatile("v_permlane32_swap_b32 %0, %1" : "+v"(u0), "+v"(u2));             \
    asm volatile("v_permlane32_swap_b32 %0, %1" : "+v"(u1), "+v"(u3));             \
    asm volatile("v_permlane32_swap_b32 %0, %1" : "+v"(u4), "+v"(u6));             \
    asm volatile("v_permlane32_swap_b32 %0, %1" : "+v"(u5), "+v"(u7));             \
    union { unsigned u[4]; short8 v8; } pa0, pa1;                                  \
    pa0.u[0] = u0; pa0.u[1] = u1; pa0.u[2] = u2; pa0.u[3] = u3;                    \
    pa1.u[0] = u4; pa1.u[1] = u5; pa1.u[2] = u6; pa1.u[3] = u7;                    \
    OACC = __builtin_amdgcn_mfma_f32_32x32x16_bf16(pa0.v8, vb0, OACC, 0, 0, 0);    \
    OACC = __builtin_amdgcn_mfma_f32_32x32x16_bf16(pa1.v8, vb1, OACC, 0, 0, 0);    \
} while (0)

__global__ __launch_bounds__(256, 4)
void fused_mfma(const unsigned short* __restrict__ vsb,
                const unsigned short* __restrict__ vstb,
                const unsigned short* __restrict__ Fb,
                float* __restrict__ part) {
    const int b = blockIdx.x;
    const int s = b & 15;
    const int qp = b >> 4;
    const int tid = threadIdx.x;
    const int wave = tid >> 6, lane = tid & 63;
    const int hi = lane >> 5, c = lane & 31;

    const int qrow0 = qp * 64 + c;
    short8 q0a = *(const short8*)(Fb + (size_t)qrow0 * 32 + 8 * hi);
    short8 q0b = *(const short8*)(Fb + (size_t)qrow0 * 32 + 16 + 8 * hi);
    short8 q1a = *(const short8*)(Fb + (size_t)(qrow0 + 32) * 32 + 8 * hi);
    short8 q1b = *(const short8*)(Fb + (size_t)(qrow0 + 32) * 32 + 16 + 8 * hi);

    f32x16 oacc0, oacc1;
#pragma unroll
    for (int r = 0; r < 16; ++r) { oacc0[r] = 0.f; oacc1[r] = 0.f; }
    float lsum0 = 0.f, lsum1 = 0.f;

    const int c1 = (125 * (s + 1)) >> 1;
    const unsigned short* vr_base = vsb + (c << 5) + (hi << 3);
    const unsigned short* vt_base = vstb + (c << 5) + (hi << 3);

    for (int ch = ((125 * s) >> 1) + wave; ch < c1; ch += 4) {
        const unsigned short* vrow = vr_base + ((size_t)ch << 10);
        short8 va0 = *(const short8*)(vrow);
        short8 va1 = *(const short8*)(vrow + 16);
        const unsigned short* vtrow = vt_base + ((size_t)ch << 10);
        short8 vb0 = *(const short8*)(vtrow);
        short8 vb1 = *(const short8*)(vtrow + 16);

        TILE(q0a, q0b, oacc0, lsum0);
        TILE(q1a, q1b, oacc1, lsum1);
    }

    // lsum: combine the two hi-halves (disjoint v-subsets per lane)
    lsum0 += __shfl_xor(lsum0, 32, 64);
    lsum1 += __shfl_xor(lsum1, 32, 64);

    // cross-wave reduce in LDS (both tiles), then write block partials
    __shared__ float red[2][4][64 * 17];   // stride 17: bank-conflict-free
    __shared__ float lred[2][4][32];
    {
        float* rw0 = &red[0][wave][lane * 17];
        float* rw1 = &red[1][wave][lane * 17];
#pragma unroll
        for (int r = 0; r < 16; ++r) { rw0[r] = oacc0[r]; rw1[r] = oacc1[r]; }
        if (hi == 0) {
            lred[0][wave][c] = lsum0;
            lred[1][wave][c] = lsum1;
        }
    }
    __syncthreads();

#pragma unroll
    for (int t = 0; t < 2; ++t) {
        const size_t pbase = (size_t)((qp * 2 + t) * NSLICE + s) * PART_STRIDE;
        for (int idx = tid; idx < 1024; idx += 256) {
            int ln = idx >> 4, r = idx & 15;
            float sum = red[t][0][ln * 17 + r] + red[t][1][ln * 17 + r]
                      + red[t][2][ln * 17 + r] + red[t][3][ln * 17 + r];
            int lhi = ln >> 5, lc = ln & 31;
            int q = (r & 3) + 8 * (r >> 2) + 4 * lhi;
            part[pbase + (q << 5) + lc] = sum;
        }
        if (tid < 32)
            part[pbase + 1024 + tid] = lred[t][0][tid] + lred[t][1][tid]
                                     + lred[t][2][tid] + lred[t][3][tid];
    }
}

// ---------------- combine slice partials ----------------
__global__ void combine_kernel(const float* __restrict__ part, float* __restrict__ out) {
    int t = blockIdx.x * 256 + threadIdx.x;      // t = qrow*32 + j
    if (t >= MROWS * 32) return;
    int qrow = t >> 5, j = t & 31;
    int qt = qrow >> 5, qi = qrow & 31;
    float a = 0.f, l = 0.f;
#pragma unroll
    for (int s = 0; s < NSLICE; ++s) {
        const float* p = part + (size_t)(qt * NSLICE + s) * PART_STRIDE;
        a += p[(qi << 5) + j];
        l += p[1024 + qi];
    }
    out[t] = a / l;
}

extern "C" void kernel_launch(void* const* d_in, const int* in_sizes, int n_in,
                              void* d_out, int out_size, void* d_ws, size_t ws_size,
                              hipStream_t stream) {
    const float* x     = (const float*)d_in[0];
    const float* W     = (const float*)d_in[1];
    const float* bias  = (const float*)d_in[2];
    const float* temps = (const float*)d_in[3];
    const float* emb   = (const float*)d_in[4];
    float* out = (float*)d_out;

    char* ws = (char*)d_ws;
    unsigned short* vsb  = (unsigned short*)(ws + OFF_VSB);
    unsigned short* vstb = (unsigned short*)(ws + OFF_VSTB);
    unsigned short* Fb   = (unsigned short*)(ws + OFF_FB);
    float*          part = (float*)(ws + OFF_PART);

    prep_kernel<<<NVS_BLOCKS + NF_BLOCKS, 256, 0, stream>>>(emb, x, W, bias, temps,
                                                            vsb, vstb, Fb);
    fused_mfma<<<64 * NSLICE, 256, 0, stream>>>(vsb, vstb, Fb, part);
    combine_kernel<<<(MROWS * 32 + 255) / 256, 256, 0, stream>>>(part, out);
}